// Round 2
// baseline (162.758 us; speedup 1.0000x reference)
//
#include <hip/hip_runtime.h>
#include <hip/hip_bf16.h>

// Problem constants (BertMultiPooler: B=32, S=4096, H=768, K=64)
#define NB 32
#define NS 4096
#define NH 768
#define NK 64
#define NM (NB * NK)   // 2048 output rows
#define ND (2 * NH)    // 1536 GEMM reduction dim
#define CHUNK 64       // rows per pool block
#define KT_TILES (ND / 64)   // 24 GEMM K-tiles of 64

typedef short short8 __attribute__((ext_vector_type(8)));
typedef float floatx4 __attribute__((ext_vector_type(4)));

__device__ __forceinline__ unsigned short f2bf(float f) {
    union { float f; unsigned u; } v; v.f = f;
    unsigned r = v.u + 0x7FFFu + ((v.u >> 16) & 1u);   // RNE to bf16
    return (unsigned short)(r >> 16);
}

// ---------------------------------------------------------------------------
// Kernel 0: zero the f32 segment-sum accumulator (graph-safe, no memset API)
// ---------------------------------------------------------------------------
__global__ __launch_bounds__(256) void zero_kernel(float4* __restrict__ p) {
    p[(size_t)blockIdx.x * 256 + threadIdx.x] = float4{0.f, 0.f, 0.f, 0.f};
}

// ---------------------------------------------------------------------------
// Kernel 1: build Wc[n][k] (bf16): k<768 -> W_dense[n][k], else W_tab[n][k-768]
// ---------------------------------------------------------------------------
__global__ __launch_bounds__(256) void wconv_kernel(const float* __restrict__ Wd,
                                                    const float* __restrict__ Wt,
                                                    unsigned short* __restrict__ Wc) {
    int i = blockIdx.x * blockDim.x + threadIdx.x;
    const int total = NH * ND / 4;
    if (i >= total) return;
    int e = i * 4;
    int n = e / ND;
    int k = e % ND;
    float4 v = (k < NH) ? *(const float4*)&Wd[n * NH + k]
                        : *(const float4*)&Wt[n * NH + (k - NH)];
    ushort4 o;
    o.x = f2bf(v.x); o.y = f2bf(v.y); o.z = f2bf(v.z); o.w = f2bf(v.w);
    *(ushort4*)&Wc[e] = o;
}

// ---------------------------------------------------------------------------
// Kernel 2: balanced segment-sum. Block (c, b) covers rows [64c, 64c+64) of
// batch b. Accumulates per-segment runs in registers, flushes partials with
// HW f32 atomics (avg ~2 flushes/block, uncontended).
// ---------------------------------------------------------------------------
__global__ __launch_bounds__(192) void pool_chunk_kernel(const float* __restrict__ hs,
                                                         const int* __restrict__ cls,
                                                         const int* __restrict__ tlen,
                                                         float* __restrict__ sums) {
    const int b  = blockIdx.y;
    const int r0 = blockIdx.x * CHUNK;
    const int tl = tlen[b];
    int rend = r0 + CHUNK;
    if (rend > tl) rend = tl;
    if (r0 >= rend) return;

    // seg = upper_bound(pos, r0) - 1, pos[k] = cls[(b*NK+k)*2+1]
    int lo = 0, hb = NK;
    while (lo < hb) {
        int mid = (lo + hb) >> 1;
        int p = cls[((b * NK + mid) << 1) + 1];
        if (p <= r0) lo = mid + 1; else hb = mid;
    }
    int seg = lo - 1;

    int r = r0;
    if (seg < 0) {                       // rows before first boundary: skipped
        int p0 = cls[(b * NK) * 2 + 1];
        r = (p0 < rend) ? p0 : rend;
        seg = 0;
        if (r >= rend) return;
    }

    const int t = threadIdx.x;           // columns 4t..4t+3
    const float4* base = (const float4*)(hs + (size_t)b * NS * NH) + t;

    while (r < rend) {
        int nb = rend;
        if (seg + 1 < NK) {
            int p = cls[((b * NK + seg + 1) << 1) + 1];
            if (p < nb) nb = p;
        }
        // accumulate rows [r, nb)
        float4 a0 = {0,0,0,0}, a1 = {0,0,0,0}, a2 = {0,0,0,0}, a3 = {0,0,0,0};
        int rr = r;
        for (; rr + 4 <= nb; rr += 4) {
            float4 v0 = base[(size_t)(rr + 0) * (NH / 4)];
            float4 v1 = base[(size_t)(rr + 1) * (NH / 4)];
            float4 v2 = base[(size_t)(rr + 2) * (NH / 4)];
            float4 v3 = base[(size_t)(rr + 3) * (NH / 4)];
            a0.x += v0.x; a0.y += v0.y; a0.z += v0.z; a0.w += v0.w;
            a1.x += v1.x; a1.y += v1.y; a1.z += v1.z; a1.w += v1.w;
            a2.x += v2.x; a2.y += v2.y; a2.z += v2.z; a2.w += v2.w;
            a3.x += v3.x; a3.y += v3.y; a3.z += v3.z; a3.w += v3.w;
        }
        for (; rr < nb; ++rr) {
            float4 v0 = base[(size_t)rr * (NH / 4)];
            a0.x += v0.x; a0.y += v0.y; a0.z += v0.z; a0.w += v0.w;
        }
        a0.x += a1.x + a2.x + a3.x;
        a0.y += a1.y + a2.y + a3.y;
        a0.z += a1.z + a2.z + a3.z;
        a0.w += a1.w + a2.w + a3.w;

        float* dst = sums + (size_t)(b * NK + seg) * NH + t * 4;
        unsafeAtomicAdd(dst + 0, a0.x);
        unsafeAtomicAdd(dst + 1, a0.y);
        unsafeAtomicAdd(dst + 2, a0.z);
        unsafeAtomicAdd(dst + 3, a0.w);
        r = nb;
        ++seg;
    }
}

// ---------------------------------------------------------------------------
// Kernel 3: finalize -> X (bf16, 2048 x 1536): pooled mean | tab gather
// ---------------------------------------------------------------------------
__global__ __launch_bounds__(192) void finalize_kernel(const float* __restrict__ hs,
                                                       const float* __restrict__ sums,
                                                       const int* __restrict__ cls,
                                                       const int* __restrict__ tlen,
                                                       unsigned short* __restrict__ X) {
    const int seg = blockIdx.x;
    const int b = seg >> 6, k = seg & 63;
    const int start = cls[seg * 2 + 1];
    const int nxt = (k == NK - 1) ? NS : cls[seg * 2 + 3];
    const int tl = tlen[b];
    const int end = (nxt < tl) ? nxt : tl;
    const float inv = 1.0f / (float)(end - start);

    const int t = threadIdx.x;
    float4 s = *(const float4*)&sums[(size_t)seg * NH + t * 4];
    const int tb = cls[seg * 2];
    float4 tv = *((const float4*)(hs + ((size_t)tb * NS + (size_t)start) * NH) + t);

    ushort4 po, ta;
    po.x = f2bf(s.x * inv); po.y = f2bf(s.y * inv);
    po.z = f2bf(s.z * inv); po.w = f2bf(s.w * inv);
    ta.x = f2bf(tv.x); ta.y = f2bf(tv.y); ta.z = f2bf(tv.z); ta.w = f2bf(tv.w);

    unsigned short* xr = X + (size_t)seg * ND;
    *(ushort4*)&xr[t * 4]      = po;
    *(ushort4*)&xr[NH + t * 4] = ta;
}

// ---------------------------------------------------------------------------
// Kernel 4: out = tanh(X @ Wc^T + b_dense + b_tab)
// M=2048, N=768, K=1536. 64x64 block tile, 4 waves (2x2), BK=64,
// LDS double-buffer, ONE barrier/iter, prefetch distance 2 (named reg sets).
// Rows padded to 72 shorts (144B) -> 2-way max bank aliasing on ds_read_b128.
// ---------------------------------------------------------------------------
__global__ __launch_bounds__(256) void gemm_kernel(const unsigned short* __restrict__ X,
                                                   const unsigned short* __restrict__ Wc,
                                                   const float* __restrict__ bd,
                                                   const float* __restrict__ bt,
                                                   float* __restrict__ out) {
    __shared__ unsigned short Al[2][64 * 72];
    __shared__ unsigned short Bl[2][64 * 72];

    const int m0 = blockIdx.x * 64;
    const int n0 = blockIdx.y * 64;
    const int tid  = threadIdx.x;
    const int lane = tid & 63;
    const int wv   = tid >> 6;
    const int wr   = wv >> 1;          // wave row (0..1)
    const int wc   = wv & 1;           // wave col (0..1)
    const int lrow = lane & 15;
    const int hi   = lane >> 4;        // 0..3
    const int srow = tid >> 2;         // staging row 0..63
    const int sc   = tid & 3;          // staging chunk base (writes sc, sc+4)

    floatx4 acc[2][2] = {};

    const uint4* gA = (const uint4*)(X  + (size_t)(m0 + srow) * ND);
    const uint4* gB = (const uint4*)(Wc + (size_t)(n0 + srow) * ND);

    uint4 vA0[2], vA1[2], vB0[2], vB1[2];   // two named prefetch sets (rule #20)

    // prologue: tile0 -> set0 -> LDS buf0 ; tile1 -> set1 (held in regs)
    vA0[0] = gA[sc];     vA0[1] = gA[sc + 4];
    vB0[0] = gB[sc];     vB0[1] = gB[sc + 4];
    *(uint4*)&Al[0][srow * 72 + sc * 8]       = vA0[0];
    *(uint4*)&Al[0][srow * 72 + (sc + 4) * 8] = vA0[1];
    *(uint4*)&Bl[0][srow * 72 + sc * 8]       = vB0[0];
    *(uint4*)&Bl[0][srow * 72 + (sc + 4) * 8] = vB0[1];
    vA1[0] = gA[8 + sc]; vA1[1] = gA[8 + sc + 4];
    vB1[0] = gB[8 + sc]; vB1[1] = gB[8 + sc + 4];

#define GEMM_COMPUTE(RB)                                                             \
    _Pragma("unroll")                                                                \
    for (int ks = 0; ks < 2; ++ks) {                                                 \
        short8 a0 = *(const short8*)&Al[RB][(wr * 32 +      lrow) * 72 + ks * 32 + hi * 8]; \
        short8 a1 = *(const short8*)&Al[RB][(wr * 32 + 16 + lrow) * 72 + ks * 32 + hi * 8]; \
        short8 b0 = *(const short8*)&Bl[RB][(wc * 32 +      lrow) * 72 + ks * 32 + hi * 8]; \
        short8 b1 = *(const short8*)&Bl[RB][(wc * 32 + 16 + lrow) * 72 + ks * 32 + hi * 8]; \
        acc[0][0] = __builtin_amdgcn_mfma_f32_16x16x32_bf16(a0, b0, acc[0][0], 0, 0, 0);    \
        acc[0][1] = __builtin_amdgcn_mfma_f32_16x16x32_bf16(a0, b1, acc[0][1], 0, 0, 0);    \
        acc[1][0] = __builtin_amdgcn_mfma_f32_16x16x32_bf16(a1, b0, acc[1][0], 0, 0, 0);    \
        acc[1][1] = __builtin_amdgcn_mfma_f32_16x16x32_bf16(a1, b1, acc[1][1], 0, 0, 0);    \
    }

// iter kt (parity P): sync; prefetch tile kt+2 -> set P; compute buf P;
// store set (P^1), which holds tile kt+1, -> buf (P^1)
#define GEMM_ITER(kt, VA_L, VB_L, VA_S, VB_S, P)                                     \
    {                                                                                \
        __syncthreads();                                                             \
        if ((kt) + 2 < KT_TILES) {                                                   \
            VA_L[0] = gA[((kt) + 2) * 8 + sc]; VA_L[1] = gA[((kt) + 2) * 8 + sc + 4];\
            VB_L[0] = gB[((kt) + 2) * 8 + sc]; VB_L[1] = gB[((kt) + 2) * 8 + sc + 4];\
        }                                                                            \
        GEMM_COMPUTE(P)                                                              \
        if ((kt) + 1 < KT_TILES) {                                                   \
            *(uint4*)&Al[P ^ 1][srow * 72 + sc * 8]       = VA_S[0];                 \
            *(uint4*)&Al[P ^ 1][srow * 72 + (sc + 4) * 8] = VA_S[1];                 \
            *(uint4*)&Bl[P ^ 1][srow * 72 + sc * 8]       = VB_S[0];                 \
            *(uint4*)&Bl[P ^ 1][srow * 72 + (sc + 4) * 8] = VB_S[1];                 \
        }                                                                            \
    }

    for (int kt = 0; kt < KT_TILES; kt += 2) {
        GEMM_ITER(kt,     vA0, vB0, vA1, vB1, 0)
        GEMM_ITER(kt + 1, vA1, vB1, vA0, vB0, 1)
    }
#undef GEMM_ITER
#undef GEMM_COMPUTE

    // Epilogue: C/D layout col = lane&15, row = (lane>>4)*4 + reg  [HW-verified]
    for (int mi = 0; mi < 2; ++mi) {
        for (int ni = 0; ni < 2; ++ni) {
            int col  = n0 + wc * 32 + ni * 16 + lrow;
            float bias = bd[col] + bt[col];
            int rowb = m0 + wr * 32 + mi * 16 + hi * 4;
            #pragma unroll
            for (int j = 0; j < 4; ++j) {
                out[(size_t)(rowb + j) * NH + col] = tanhf(acc[mi][ni][j] + bias);
            }
        }
    }
}

// ---------------------------------------------------------------------------
extern "C" void kernel_launch(void* const* d_in, const int* in_sizes, int n_in,
                              void* d_out, int out_size, void* d_ws, size_t ws_size,
                              hipStream_t stream) {
    const float* hs  = (const float*)d_in[0];   // hidden_states (B,S,H) f32
    const float* Wd  = (const float*)d_in[1];   // W_dense (H,H)
    const float* bd  = (const float*)d_in[2];   // b_dense (H,)
    const float* Wt  = (const float*)d_in[3];   // W_tab (H,H)
    const float* bt  = (const float*)d_in[4];   // b_tab (H,)
    const int*   cls = (const int*)d_in[5];     // cls_indexes (B*K, 2) as int32
    const int*   tl  = (const int*)d_in[6];     // table_length (B,) as int32
    float* out = (float*)d_out;

    float*          sums = (float*)d_ws;                       // 2048*768 f32 = 6.3 MB
    unsigned short* Wc   = (unsigned short*)(sums + (size_t)NM * NH); // 768*1536 bf16
    unsigned short* X    = Wc + (size_t)NH * ND;               // 2048*1536 bf16

    // zero the accumulator (NM*NH/4 = 393216 float4s = 1536 blocks x 256)
    zero_kernel<<<dim3(NM * NH / 4 / 256), 256, 0, stream>>>((float4*)sums);
    // weights convert
    wconv_kernel<<<dim3((NH * ND / 4 + 255) / 256), 256, 0, stream>>>(Wd, Wt, Wc);
    // balanced segment-sum (grid: 64 chunks x 32 batches)
    pool_chunk_kernel<<<dim3(NS / CHUNK, NB), 192, 0, stream>>>(hs, cls, tl, sums);
    // finalize: mean + tab gather -> X bf16
    finalize_kernel<<<dim3(NM), 192, 0, stream>>>(hs, sums, cls, tl, X);
    // fused GEMM + bias + tanh
    gemm_kernel<<<dim3(NM / 64, NH / 64), 256, 0, stream>>>(X, Wc, bd, bt, out);
}